// Round 11
// baseline (7718.430 us; speedup 1.0000x reference)
//
#include <hip/hip_runtime.h>

// LSTM T=4096, IN=32, H=512, OUT=32, 3 layers + projection.
// R11 = R10 (readlane dot, per-wave poll) with the two per-step __syncthreads
//   removed. R10 post-mortem: barriers serialized poll-detect jitter across
//   all 16 waves and blocked t+1 polling behind the wave0 tail (~1500 cyc).
//   Replacement: tagged LDS flag protocol.
//   - wave wv: poll -> dot -> part[pb] write -> release pflag[pb][wv]=t+1,
//     then rolls STRAIGHT into step t+1 (overlaps tail + remote roundtrip).
//   - wave 0: spins on the 16 flags (lanes 0-15, __all), sums partials,
//     sets tdone=t+1 (frees part[pb] for step t+2), gates, ONE coalesced
//     128B publish (lanes 0-15).
//   - anti-race: before overwriting part[u&1] at step u, wait tdone>=u-1
//     (normally already true; prevents upstream-layer waves sprinting 2+
//     steps ahead of the local tail).
//   - tags make flag reset unnecessary; part[] double-buffered by t&1.
// Invariants: no cache-wide fences (R2); no runtime indexing of private
//   arrays (R4); <=64 weight floats/lane (R5/R6/R8); publish = one wave one
//   full line (R6); register-only broadcast in the dot (R9/R10).

#define T_SEQ 4096
#define HDIM  512
#define NWG_L 32
#define NTH   1024

typedef unsigned long long u64;

__device__ __forceinline__ u64 cohLoad(const u64* p) {
    return __hip_atomic_load(p, __ATOMIC_RELAXED, __HIP_MEMORY_SCOPE_AGENT);
}
__device__ __forceinline__ void cohStore(u64* p, u64 v) {
    __hip_atomic_store(p, v, __ATOMIC_RELAXED, __HIP_MEMORY_SCOPE_AGENT);
}
__device__ __forceinline__ float fsigmoid(float x) {
    return __builtin_amdgcn_rcpf(1.f + __expf(-x));
}
__device__ __forceinline__ float ftanh(float x) {
    float e = __expf(2.f * fabsf(x));           // +inf ok -> t = 1
    float t = 1.f - 2.f * __builtin_amdgcn_rcpf(e + 1.f);
    return copysignf(t, x);
}
__device__ __forceinline__ float bcast(float v, int k) {
    return __uint_as_float(__builtin_amdgcn_readlane(__float_as_uint(v), k));
}

// ---------------------------------------------------------------------------
// Tiled fp32 GEMM (final projection): C[M][N] = A[M][K] * B[N][K]^T + bias[n]
// ---------------------------------------------------------------------------
template <int BM, int BN, int BK>
__global__ __launch_bounds__(256)
void gemm_abt(const float* __restrict__ A, const float* __restrict__ B,
              const float* __restrict__ bias1,
              float* __restrict__ C, int M, int N, int K) {
    constexpr int NTX = BN / 4;
    constexpr int NTY = 256 / NTX;
    constexpr int TM  = BM / NTY;
    __shared__ float As[BM][BK + 1];
    __shared__ float Bs[BN][BK + 1];

    const int tid = threadIdx.x;
    const int tx = tid % NTX;
    const int ty = tid / NTX;
    const int m0 = blockIdx.y * BM;
    const int n0 = blockIdx.x * BN;

    float acc[TM][4];
    #pragma unroll
    for (int i = 0; i < TM; ++i)
        #pragma unroll
        for (int j = 0; j < 4; ++j) acc[i][j] = 0.f;

    for (int k0 = 0; k0 < K; k0 += BK) {
        constexpr int AV = BM * BK / 4;
        #pragma unroll
        for (int i = tid; i < AV; i += 256) {
            int r = i / (BK / 4), c4 = i % (BK / 4);
            float4 v = *(const float4*)(A + (size_t)(m0 + r) * K + k0 + c4 * 4);
            As[r][c4 * 4 + 0] = v.x; As[r][c4 * 4 + 1] = v.y;
            As[r][c4 * 4 + 2] = v.z; As[r][c4 * 4 + 3] = v.w;
        }
        constexpr int BV = BN * BK / 4;
        #pragma unroll
        for (int i = tid; i < BV; i += 256) {
            int r = i / (BK / 4), c4 = i % (BK / 4);
            float4 v = *(const float4*)(B + (size_t)(n0 + r) * K + k0 + c4 * 4);
            Bs[r][c4 * 4 + 0] = v.x; Bs[r][c4 * 4 + 1] = v.y;
            Bs[r][c4 * 4 + 2] = v.z; Bs[r][c4 * 4 + 3] = v.w;
        }
        __syncthreads();
        #pragma unroll
        for (int kk = 0; kk < BK; ++kk) {
            float a[TM], b[4];
            #pragma unroll
            for (int i = 0; i < TM; ++i) a[i] = As[ty * TM + i][kk];
            #pragma unroll
            for (int j = 0; j < 4; ++j) b[j] = Bs[tx * 4 + j][kk];
            #pragma unroll
            for (int i = 0; i < TM; ++i)
                #pragma unroll
                for (int j = 0; j < 4; ++j) acc[i][j] += a[i] * b[j];
        }
        __syncthreads();
    }

    #pragma unroll
    for (int j = 0; j < 4; ++j) {
        float bv = bias1 ? bias1[n0 + tx * 4 + j] : 0.f;
        #pragma unroll
        for (int i = 0; i < TM; ++i) acc[i][j] += bv;
    }
    #pragma unroll
    for (int i = 0; i < TM; ++i) {
        int m = m0 + ty * TM + i;
        float4 v = make_float4(acc[i][0], acc[i][1], acc[i][2], acc[i][3]);
        *(float4*)(C + (size_t)m * N + n0 + tx * 4) = v;
    }
}

// ---------------------------------------------------------------------------
__global__ void unpack_h(const u64* __restrict__ hp, float* __restrict__ out,
                         int n) {
    int i = blockIdx.x * blockDim.x + threadIdx.x;
    if (i < n) out[i] = __uint_as_float((unsigned)hp[i]);
}

// ---------------------------------------------------------------------------
// 32 WGs/layer x 1024 thr (16 waves). Lane = row (gate*16 + col_local).
// Layers 1/2: wave wv owns k-chunk [wv*64,+64) of concat [prev-h; own-h]:
//   wv<8 -> prev-h / Wih, wv>=8 -> own-h / Whh. Lane polls one element into
//   a VGPR; dot = 64x readlane-broadcast + fmac against w[64].
// Layer 0: wave wv owns own-h k [wv*32,+32) (lanes 0-31 poll); wave 15 also
//   handles x (32 floats of seq, weights in w[32..63]).
// ---------------------------------------------------------------------------
__global__ __launch_bounds__(NTH, 4)
void lstm_fused(const float* __restrict__ seq,
                const float* __restrict__ Wih1, const float* __restrict__ Whh1,
                const float* __restrict__ bih1, const float* __restrict__ bhh1,
                const float* __restrict__ Wih2, const float* __restrict__ Whh2,
                const float* __restrict__ bih2, const float* __restrict__ bhh2,
                const float* __restrict__ Wih3, const float* __restrict__ Whh3,
                const float* __restrict__ bih3, const float* __restrict__ bhh3,
                u64* __restrict__ hp) {
    __shared__ float part[2][NTH];      // [pb][wv*64 + row]
    __shared__ int   pflag[2][16];      // [pb][wv] = t+1 when partial ready
    __shared__ int   tdone;             // = t+1 when wave0 finished part reads

    const int blk   = blockIdx.x;
    const int layer = blk >> 5;
    const int g     = blk & 31;
    const int tid   = threadIdx.x;
    const int wv    = tid >> 6;          // 0..15
    const int lane  = tid & 63;          // = row (gate*16 + col_local)
    const int grow  = (lane >> 4) * HDIM + g * 16 + (lane & 15);

    const float* Wih = layer == 0 ? Wih1 : (layer == 1 ? Wih2 : Wih3);
    const float* Whh = layer == 0 ? Whh1 : (layer == 1 ? Whh2 : Whh3);
    const float* bih = layer == 0 ? bih1 : (layer == 1 ? bih2 : bih3);
    const float* bhh = layer == 0 ? bhh1 : (layer == 1 ? bhh2 : bhh3);

    if (tid < 16) { pflag[0][tid] = 0; pflag[1][tid] = 0; }
    if (tid == 0) tdone = 0;

    // ---- 64 weight floats/lane (loop-constant indexing only) ----
    float w[64];
    #pragma unroll
    for (int m = 0; m < 64; ++m) w[m] = 0.f;
    if (layer == 0) {
        const float* wp = Whh + (size_t)grow * HDIM + wv * 32;
        #pragma unroll
        for (int i = 0; i < 8; ++i) {
            float4 v = ((const float4*)wp)[i];
            w[4*i+0]=v.x; w[4*i+1]=v.y; w[4*i+2]=v.z; w[4*i+3]=v.w;
        }
        if (wv == 15) {   // x weights -> w[32..63]
            const float* xp = Wih + (size_t)grow * 32;
            #pragma unroll
            for (int i = 0; i < 8; ++i) {
                float4 v = ((const float4*)xp)[i];
                w[32+4*i+0]=v.x; w[32+4*i+1]=v.y;
                w[32+4*i+2]=v.z; w[32+4*i+3]=v.w;
            }
        }
    } else {
        const float* wp = (wv < 8)
            ? Wih + (size_t)grow * HDIM + wv * 64
            : Whh + (size_t)grow * HDIM + (wv - 8) * 64;
        #pragma unroll
        for (int i = 0; i < 16; ++i) {
            float4 v = ((const float4*)wp)[i];
            w[4*i+0]=v.x; w[4*i+1]=v.y; w[4*i+2]=v.z; w[4*i+3]=v.w;
        }
    }
    #pragma unroll
    for (int m = 0; m < 64; ++m) asm volatile("" : "+v"(w[m]));

    const float brow = bih[grow] + bhh[grow];

    u64*       hpOwn  = hp + (size_t)layer * T_SEQ * HDIM;
    const u64* hpPrev = hp + (size_t)(layer > 0 ? layer - 1 : 0) * T_SEQ * HDIM;

    __syncthreads();    // covers pflag/tdone init (only barrier in kernel)
    if (wv == 0) __builtin_amdgcn_s_setprio(1);

    float c = 0.f;   // cell state (wave 0, lanes 0..15)

    for (unsigned t = 0; t < T_SEQ; ++t) {
        const int pb = t & 1;

        // ---- per-wave poll: chunk element straight into a VGPR ----
        float hval = 0.f;
        float xval = 0.f;
        if (layer == 0) {
            if (lane < 32 && t > 0) {
                const u64* ph = hpOwn + (size_t)(t - 1) * HDIM + wv * 32 + lane;
                u64 v;
                do { v = cohLoad(ph); } while ((unsigned)(v >> 32) != t);
                hval = __uint_as_float((unsigned)v);
            }
            if (wv == 15 && lane < 32)
                xval = seq[(size_t)t * 32 + lane];
        } else {
            if (wv < 8) {                        // prev-layer h[t], tag t+1
                const u64* px = hpPrev + (size_t)t * HDIM + wv * 64 + lane;
                u64 v;
                do { v = cohLoad(px); } while ((unsigned)(v >> 32) != t + 1u);
                hval = __uint_as_float((unsigned)v);
            } else if (t > 0) {                  // own h[t-1], tag t
                const u64* ph = hpOwn + (size_t)(t - 1) * HDIM
                              + (wv - 8) * 64 + lane;
                u64 v;
                do { v = cohLoad(ph); } while ((unsigned)(v >> 32) != t);
                hval = __uint_as_float((unsigned)v);
            }
        }

        // ---- dot: readlane broadcast + fmac, NO LDS ----
        float pe = 0.f, po = 0.f;
        if (layer == 0) {
            #pragma unroll
            for (int k = 0; k < 32; k += 2) {
                pe = fmaf(bcast(hval, k),     w[k],     pe);
                po = fmaf(bcast(hval, k + 1), w[k + 1], po);
            }
            if (wv == 15) {
                #pragma unroll
                for (int k = 0; k < 32; k += 2) {
                    pe = fmaf(bcast(xval, k),     w[32 + k],     pe);
                    po = fmaf(bcast(xval, k + 1), w[32 + k + 1], po);
                }
            }
        } else {
            #pragma unroll
            for (int k = 0; k < 64; k += 2) {
                pe = fmaf(bcast(hval, k),     w[k],     pe);
                po = fmaf(bcast(hval, k + 1), w[k + 1], po);
            }
        }

        // ---- guard part[pb] reuse: tail of step t-2 must have read it ----
        if (t >= 2) {
            while ((unsigned)__hip_atomic_load(&tdone, __ATOMIC_ACQUIRE,
                                   __HIP_MEMORY_SCOPE_WORKGROUP) < t - 1u) {}
        }
        part[pb][wv * 64 + lane] = pe + po;
        if (lane == 0)
            __hip_atomic_store(&pflag[pb][wv], (int)(t + 1), __ATOMIC_RELEASE,
                               __HIP_MEMORY_SCOPE_WORKGROUP);

        // ---- wave 0: flag-spin, sum, gates, ONE coalesced 128B publish ----
        if (wv == 0) {
            const int need = (int)(t + 1);
            bool ok;
            do {
                int f = (lane < 16)
                    ? __hip_atomic_load(&pflag[pb][lane], __ATOMIC_ACQUIRE,
                                        __HIP_MEMORY_SCOPE_WORKGROUP)
                    : need;
                ok = (f == need);
            } while (!__all(ok));

            float tot = brow;
            #pragma unroll
            for (int wvv = 0; wvv < 16; ++wvv) tot += part[pb][wvv * 64 + lane];
            if (lane == 0)
                __hip_atomic_store(&tdone, (int)(t + 1), __ATOMIC_RELEASE,
                                   __HIP_MEMORY_SCOPE_WORKGROUP);

            // gates: compute both activations on all 64 lanes (2 exp, not 6)
            float sgv = fsigmoid(tot);
            float thv = ftanh(tot);
            float act = (lane >= 32 && lane < 48) ? thv : sgv;
            const int c16 = lane & 15;
            float fv = __shfl(act, c16 + 16, 64);
            float gv = __shfl(act, c16 + 32, 64);
            float ov = __shfl(act, c16 + 48, 64);
            if (lane < 16) {
                c = fv * c + act * gv;          // act = i-gate for lanes 0-15
                float h = ov * ftanh(c);
                u64 pkt = (u64)__float_as_uint(h) | ((u64)(t + 1u) << 32);
                cohStore(hpOwn + (size_t)t * HDIM + g * 16 + lane, pkt);
            }
        }
        // No barrier: waves roll straight into polling t+1. part[] reuse is
        // guarded by tdone; pflag is tag-checked (stale t-1 values harmless;
        // t+3 writes are blocked by the tdone chain until wave0 passes t).
    }
}

// ---------------------------------------------------------------------------
extern "C" void kernel_launch(void* const* d_in, const int* in_sizes, int n_in,
                              void* d_out, int out_size, void* d_ws, size_t ws_size,
                              hipStream_t stream) {
    const float* seq   = (const float*)d_in[0];
    const float* W_ih1 = (const float*)d_in[1];
    const float* W_hh1 = (const float*)d_in[2];
    const float* b_ih1 = (const float*)d_in[3];
    const float* b_hh1 = (const float*)d_in[4];
    const float* W_ih2 = (const float*)d_in[5];
    const float* W_hh2 = (const float*)d_in[6];
    const float* b_ih2 = (const float*)d_in[7];
    const float* b_hh2 = (const float*)d_in[8];
    const float* W_ih3 = (const float*)d_in[9];
    const float* W_hh3 = (const float*)d_in[10];
    const float* b_ih3 = (const float*)d_in[11];
    const float* b_hh3 = (const float*)d_in[12];
    const float* W_out = (const float*)d_in[13];
    const float* b_out = (const float*)d_in[14];
    float* out = (float*)d_out;

    // Workspace: hp[3][T][512] packed u64 (50.3MB); hs2 floats reuse the
    // dead layer-0 packed region after the recurrence.
    u64*   hp   = (u64*)d_ws;
    float* hs2f = (float*)d_ws;
    const u64* hp2 = hp + (size_t)2 * T_SEQ * HDIM;

    hipMemsetAsync(hp, 0, (size_t)3 * T_SEQ * HDIM * sizeof(u64), stream);

    lstm_fused<<<3 * NWG_L, NTH, 0, stream>>>(
        seq, W_ih1, W_hh1, b_ih1, b_hh1, W_ih2, W_hh2, b_ih2, b_hh2,
        W_ih3, W_hh3, b_ih3, b_hh3, hp);

    const int n = T_SEQ * HDIM;
    unpack_h<<<(n + 255) / 256, 256, 0, stream>>>(hp2, hs2f, n);

    gemm_abt<64, 32, 32><<<dim3(1, T_SEQ / 64), 256, 0, stream>>>(
        hs2f, W_out, b_out, out, T_SEQ, 32, HDIM);
}

// Round 12
// 7291.715 us; speedup vs baseline: 1.0585x; 1.0585x over previous
//
#include <hip/hip_runtime.h>

// LSTM T=4096, IN=32, H=512, OUT=32, 3 layers + projection.
// R12 = R10 (proven best: readlane dot, per-wave poll, ONE s_barrier/step)
//   + 2-deep pipelined polling + all-lane activation tail + wave0 setprio.
//   R11 post-mortem: replacing the barrier with LDS flags REGRESSED 23% —
//   s_barrier is near-free and parks non-critical waves, giving the
//   critical own-h waves uncontended SIMD issue. Keep the barrier.
//   R12's target: poll sampling aliasing. A serial poll loop samples the
//   location once per MALL RTT (~500 cyc), adding ~0.5 RTT to every detect.
//   Two in-flight loads (check oldest, keep newest flying) sample every
//   ~50 cyc instead.
// Invariants: no cache-wide fences (R2); no runtime indexing of private
//   arrays (R4); <=64 weight floats/lane (R5/R6/R8); publish = one wave one
//   full 128B line (R6); register-only broadcast in the dot (R9/R10);
//   one s_barrier per step, no hand-rolled WG sync (R11).

#define T_SEQ 4096
#define HDIM  512
#define NWG_L 32
#define NTH   1024

typedef unsigned long long u64;

__device__ __forceinline__ u64 cohLoad(const u64* p) {
    return __hip_atomic_load(p, __ATOMIC_RELAXED, __HIP_MEMORY_SCOPE_AGENT);
}
__device__ __forceinline__ void cohStore(u64* p, u64 v) {
    __hip_atomic_store(p, v, __ATOMIC_RELAXED, __HIP_MEMORY_SCOPE_AGENT);
}
// 2-deep pipelined tag-poll: keeps one load in flight while checking the
// older one -> samples the address every ~loop-overhead instead of every RTT.
__device__ __forceinline__ float pollTag(const u64* p, unsigned want) {
    u64 v0 = cohLoad(p);
    u64 v1 = cohLoad(p);
    while ((unsigned)(v0 >> 32) != want) {
        v0 = v1;
        v1 = cohLoad(p);
    }
    return __uint_as_float((unsigned)v0);
}
__device__ __forceinline__ float fsigmoid(float x) {
    return __builtin_amdgcn_rcpf(1.f + __expf(-x));
}
__device__ __forceinline__ float ftanh(float x) {
    float e = __expf(2.f * fabsf(x));           // +inf ok -> t = 1
    float t = 1.f - 2.f * __builtin_amdgcn_rcpf(e + 1.f);
    return copysignf(t, x);
}
__device__ __forceinline__ float bcast(float v, int k) {
    return __uint_as_float(__builtin_amdgcn_readlane(__float_as_uint(v), k));
}

// ---------------------------------------------------------------------------
// Tiled fp32 GEMM (final projection): C[M][N] = A[M][K] * B[N][K]^T + bias[n]
// ---------------------------------------------------------------------------
template <int BM, int BN, int BK>
__global__ __launch_bounds__(256)
void gemm_abt(const float* __restrict__ A, const float* __restrict__ B,
              const float* __restrict__ bias1,
              float* __restrict__ C, int M, int N, int K) {
    constexpr int NTX = BN / 4;
    constexpr int NTY = 256 / NTX;
    constexpr int TM  = BM / NTY;
    __shared__ float As[BM][BK + 1];
    __shared__ float Bs[BN][BK + 1];

    const int tid = threadIdx.x;
    const int tx = tid % NTX;
    const int ty = tid / NTX;
    const int m0 = blockIdx.y * BM;
    const int n0 = blockIdx.x * BN;

    float acc[TM][4];
    #pragma unroll
    for (int i = 0; i < TM; ++i)
        #pragma unroll
        for (int j = 0; j < 4; ++j) acc[i][j] = 0.f;

    for (int k0 = 0; k0 < K; k0 += BK) {
        constexpr int AV = BM * BK / 4;
        #pragma unroll
        for (int i = tid; i < AV; i += 256) {
            int r = i / (BK / 4), c4 = i % (BK / 4);
            float4 v = *(const float4*)(A + (size_t)(m0 + r) * K + k0 + c4 * 4);
            As[r][c4 * 4 + 0] = v.x; As[r][c4 * 4 + 1] = v.y;
            As[r][c4 * 4 + 2] = v.z; As[r][c4 * 4 + 3] = v.w;
        }
        constexpr int BV = BN * BK / 4;
        #pragma unroll
        for (int i = tid; i < BV; i += 256) {
            int r = i / (BK / 4), c4 = i % (BK / 4);
            float4 v = *(const float4*)(B + (size_t)(n0 + r) * K + k0 + c4 * 4);
            Bs[r][c4 * 4 + 0] = v.x; Bs[r][c4 * 4 + 1] = v.y;
            Bs[r][c4 * 4 + 2] = v.z; Bs[r][c4 * 4 + 3] = v.w;
        }
        __syncthreads();
        #pragma unroll
        for (int kk = 0; kk < BK; ++kk) {
            float a[TM], b[4];
            #pragma unroll
            for (int i = 0; i < TM; ++i) a[i] = As[ty * TM + i][kk];
            #pragma unroll
            for (int j = 0; j < 4; ++j) b[j] = Bs[tx * 4 + j][kk];
            #pragma unroll
            for (int i = 0; i < TM; ++i)
                #pragma unroll
                for (int j = 0; j < 4; ++j) acc[i][j] += a[i] * b[j];
        }
        __syncthreads();
    }

    #pragma unroll
    for (int j = 0; j < 4; ++j) {
        float bv = bias1 ? bias1[n0 + tx * 4 + j] : 0.f;
        #pragma unroll
        for (int i = 0; i < TM; ++i) acc[i][j] += bv;
    }
    #pragma unroll
    for (int i = 0; i < TM; ++i) {
        int m = m0 + ty * TM + i;
        float4 v = make_float4(acc[i][0], acc[i][1], acc[i][2], acc[i][3]);
        *(float4*)(C + (size_t)m * N + n0 + tx * 4) = v;
    }
}

// ---------------------------------------------------------------------------
__global__ void unpack_h(const u64* __restrict__ hp, float* __restrict__ out,
                         int n) {
    int i = blockIdx.x * blockDim.x + threadIdx.x;
    if (i < n) out[i] = __uint_as_float((unsigned)hp[i]);
}

// ---------------------------------------------------------------------------
// 32 WGs/layer x 1024 thr (16 waves). Lane = row (gate*16 + col_local).
// Layers 1/2: wave wv owns k-chunk [wv*64,+64) of concat [prev-h; own-h]:
//   wv<8 -> prev-h / Wih, wv>=8 -> own-h / Whh. Lane polls one element into
//   a VGPR; dot = 64x readlane-broadcast + fmac against w[64].
// Layer 0: wave wv owns own-h k [wv*32,+32) (lanes 0-31 poll); wave 15 also
//   handles x (32 floats of seq, weights in w[32..63]).
// ---------------------------------------------------------------------------
__global__ __launch_bounds__(NTH, 4)
void lstm_fused(const float* __restrict__ seq,
                const float* __restrict__ Wih1, const float* __restrict__ Whh1,
                const float* __restrict__ bih1, const float* __restrict__ bhh1,
                const float* __restrict__ Wih2, const float* __restrict__ Whh2,
                const float* __restrict__ bih2, const float* __restrict__ bhh2,
                const float* __restrict__ Wih3, const float* __restrict__ Whh3,
                const float* __restrict__ bih3, const float* __restrict__ bhh3,
                u64* __restrict__ hp) {
    __shared__ float part[2][NTH];      // [pb][wv*64 + row]

    const int blk   = blockIdx.x;
    const int layer = blk >> 5;
    const int g     = blk & 31;
    const int tid   = threadIdx.x;
    const int wv    = tid >> 6;          // 0..15
    const int lane  = tid & 63;          // = row (gate*16 + col_local)
    const int grow  = (lane >> 4) * HDIM + g * 16 + (lane & 15);

    const float* Wih = layer == 0 ? Wih1 : (layer == 1 ? Wih2 : Wih3);
    const float* Whh = layer == 0 ? Whh1 : (layer == 1 ? Whh2 : Whh3);
    const float* bih = layer == 0 ? bih1 : (layer == 1 ? bih2 : bih3);
    const float* bhh = layer == 0 ? bhh1 : (layer == 1 ? bhh2 : bhh3);

    // ---- 64 weight floats/lane (loop-constant indexing only) ----
    float w[64];
    #pragma unroll
    for (int m = 0; m < 64; ++m) w[m] = 0.f;
    if (layer == 0) {
        const float* wp = Whh + (size_t)grow * HDIM + wv * 32;
        #pragma unroll
        for (int i = 0; i < 8; ++i) {
            float4 v = ((const float4*)wp)[i];
            w[4*i+0]=v.x; w[4*i+1]=v.y; w[4*i+2]=v.z; w[4*i+3]=v.w;
        }
        if (wv == 15) {   // x weights -> w[32..63]
            const float* xp = Wih + (size_t)grow * 32;
            #pragma unroll
            for (int i = 0; i < 8; ++i) {
                float4 v = ((const float4*)xp)[i];
                w[32+4*i+0]=v.x; w[32+4*i+1]=v.y;
                w[32+4*i+2]=v.z; w[32+4*i+3]=v.w;
            }
        }
    } else {
        const float* wp = (wv < 8)
            ? Wih + (size_t)grow * HDIM + wv * 64
            : Whh + (size_t)grow * HDIM + (wv - 8) * 64;
        #pragma unroll
        for (int i = 0; i < 16; ++i) {
            float4 v = ((const float4*)wp)[i];
            w[4*i+0]=v.x; w[4*i+1]=v.y; w[4*i+2]=v.z; w[4*i+3]=v.w;
        }
    }
    #pragma unroll
    for (int m = 0; m < 64; ++m) asm volatile("" : "+v"(w[m]));

    const float brow = bih[grow] + bhh[grow];

    u64*       hpOwn  = hp + (size_t)layer * T_SEQ * HDIM;
    const u64* hpPrev = hp + (size_t)(layer > 0 ? layer - 1 : 0) * T_SEQ * HDIM;

    if (wv == 0) __builtin_amdgcn_s_setprio(1);

    float c = 0.f;   // cell state (wave 0, lanes 0..15)

    for (unsigned t = 0; t < T_SEQ; ++t) {
        const int pb = t & 1;

        // ---- per-wave poll (2-deep pipelined): element -> VGPR ----
        float hval = 0.f;
        float xval = 0.f;
        if (layer == 0) {
            if (lane < 32 && t > 0)
                hval = pollTag(hpOwn + (size_t)(t - 1) * HDIM + wv * 32 + lane, t);
            if (wv == 15 && lane < 32)
                xval = seq[(size_t)t * 32 + lane];
        } else {
            if (wv < 8) {                        // prev-layer h[t], tag t+1
                hval = pollTag(hpPrev + (size_t)t * HDIM + wv * 64 + lane, t + 1u);
            } else if (t > 0) {                  // own h[t-1], tag t
                hval = pollTag(hpOwn + (size_t)(t - 1) * HDIM + (wv - 8) * 64 + lane, t);
            }
        }

        // ---- dot: readlane broadcast + fmac, NO LDS ----
        float pe = 0.f, po = 0.f;
        if (layer == 0) {
            #pragma unroll
            for (int k = 0; k < 32; k += 2) {
                pe = fmaf(bcast(hval, k),     w[k],     pe);
                po = fmaf(bcast(hval, k + 1), w[k + 1], po);
            }
            if (wv == 15) {
                #pragma unroll
                for (int k = 0; k < 32; k += 2) {
                    pe = fmaf(bcast(xval, k),     w[32 + k],     pe);
                    po = fmaf(bcast(xval, k + 1), w[32 + k + 1], po);
                }
            }
        } else {
            #pragma unroll
            for (int k = 0; k < 64; k += 2) {
                pe = fmaf(bcast(hval, k),     w[k],     pe);
                po = fmaf(bcast(hval, k + 1), w[k + 1], po);
            }
        }
        part[pb][wv * 64 + lane] = pe + po;
        __syncthreads();

        // ---- wave 0: cross-wave sum, gates, ONE coalesced 128B publish ----
        if (wv == 0) {
            float tot = brow;
            #pragma unroll
            for (int wvv = 0; wvv < 16; ++wvv) tot += part[pb][wvv * 64 + lane];
            // activations on all 64 lanes (2 transcendental paths, not 6)
            float sgv = fsigmoid(tot);
            float thv = ftanh(tot);
            float act = (lane >= 32 && lane < 48) ? thv : sgv;
            const int c16 = lane & 15;
            float fv = __shfl(act, c16 + 16, 64);
            float gv = __shfl(act, c16 + 32, 64);
            float ov = __shfl(act, c16 + 48, 64);
            if (lane < 16) {
                c = fv * c + act * gv;          // act = i-gate on lanes 0-15
                float h = ov * ftanh(c);
                u64 pkt = (u64)__float_as_uint(h) | ((u64)(t + 1u) << 32);
                cohStore(hpOwn + (size_t)t * HDIM + g * 16 + lane, pkt);
            }
        }
        // Other waves roll straight into polling t+1 (single barrier/step;
        // part[] double-buffered: writes to part[pb] recur at t+2, after
        // barrier(t+1), which wave 0 joins only after its tail(t) reads).
    }
}

// ---------------------------------------------------------------------------
extern "C" void kernel_launch(void* const* d_in, const int* in_sizes, int n_in,
                              void* d_out, int out_size, void* d_ws, size_t ws_size,
                              hipStream_t stream) {
    const float* seq   = (const float*)d_in[0];
    const float* W_ih1 = (const float*)d_in[1];
    const float* W_hh1 = (const float*)d_in[2];
    const float* b_ih1 = (const float*)d_in[3];
    const float* b_hh1 = (const float*)d_in[4];
    const float* W_ih2 = (const float*)d_in[5];
    const float* W_hh2 = (const float*)d_in[6];
    const float* b_ih2 = (const float*)d_in[7];
    const float* b_hh2 = (const float*)d_in[8];
    const float* W_ih3 = (const float*)d_in[9];
    const float* W_hh3 = (const float*)d_in[10];
    const float* b_ih3 = (const float*)d_in[11];
    const float* b_hh3 = (const float*)d_in[12];
    const float* W_out = (const float*)d_in[13];
    const float* b_out = (const float*)d_in[14];
    float* out = (float*)d_out;

    // Workspace: hp[3][T][512] packed u64 (50.3MB); hs2 floats reuse the
    // dead layer-0 packed region after the recurrence.
    u64*   hp   = (u64*)d_ws;
    float* hs2f = (float*)d_ws;
    const u64* hp2 = hp + (size_t)2 * T_SEQ * HDIM;

    hipMemsetAsync(hp, 0, (size_t)3 * T_SEQ * HDIM * sizeof(u64), stream);

    lstm_fused<<<3 * NWG_L, NTH, 0, stream>>>(
        seq, W_ih1, W_hh1, b_ih1, b_hh1, W_ih2, W_hh2, b_ih2, b_hh2,
        W_ih3, W_hh3, b_ih3, b_hh3, hp);

    const int n = T_SEQ * HDIM;
    unpack_h<<<(n + 255) / 256, 256, 0, stream>>>(hp2, hs2f, n);

    gemm_abt<64, 32, 32><<<dim3(1, T_SEQ / 64), 256, 0, stream>>>(
        hs2f, W_out, b_out, out, T_SEQ, 32, HDIM);
}

// Round 13
// 6256.530 us; speedup vs baseline: 1.2337x; 1.1655x over previous
//
#include <hip/hip_runtime.h>

// LSTM T=4096, IN=32, H=512, OUT=32, 3 layers + projection.
// R13 = exact revert to R10, the measured optimum of this structure.
//   Session gradient map around R10 (all falsified, all reverted):
//     - LDS-dot repartitions (R8 4rx16k, R9 2rx32k): 1.8-2.2x regressions —
//       intra-wave LDS address divergence + cross-half shfl is the expensive
//       case; R10's register-broadcast (readlane) dot avoids LDS entirely.
//     - barrier removal via LDS flag protocol (R11): +21% — s_barrier is
//       near-free and parks non-critical waves; hand-rolled sync loses.
//     - 2-deep pipelined polling (R12): +15% — denser poll sampling adds
//       MALL contention on the published lines; RTT-paced polling is right.
//   Remaining time is the structural floor: per step, h (512 wide) makes an
//   all-to-all hop between 32 WGs through the MALL (the only XCD-coherent
//   point; G16 forbids relying on same-XCD placement). Step = 1.51us ~=
//   3640 cyc ~= store visibility + poll RTT + dot issue + barrier + tail.
// Protocol (hard-won invariants):
//   - packed u64 {seq-tag:32 | value:32}: the flag IS the data (R3);
//   - relaxed agent-scope atomics only, NO cache-wide fences (R2);
//   - <=64 weight floats/lane, loop-constant indexing (R4/R5/R6/R8);
//   - publish = ONE wave storing ONE full 128B line (R6);
//   - per-wave poll straight into VGPRs, readlane-broadcast dot (R10);
//   - ONE s_barrier per step, part[] double-buffered (R10/R11).

#define T_SEQ 4096
#define HDIM  512
#define NWG_L 32
#define NTH   1024

typedef unsigned long long u64;

__device__ __forceinline__ u64 cohLoad(const u64* p) {
    return __hip_atomic_load(p, __ATOMIC_RELAXED, __HIP_MEMORY_SCOPE_AGENT);
}
__device__ __forceinline__ void cohStore(u64* p, u64 v) {
    __hip_atomic_store(p, v, __ATOMIC_RELAXED, __HIP_MEMORY_SCOPE_AGENT);
}
__device__ __forceinline__ float fsigmoid(float x) {
    return __builtin_amdgcn_rcpf(1.f + __expf(-x));
}
__device__ __forceinline__ float ftanh(float x) {
    float e = __expf(2.f * fabsf(x));           // +inf ok -> t = 1
    float t = 1.f - 2.f * __builtin_amdgcn_rcpf(e + 1.f);
    return copysignf(t, x);
}
__device__ __forceinline__ float bcast(float v, int k) {
    return __uint_as_float(__builtin_amdgcn_readlane(__float_as_uint(v), k));
}

// ---------------------------------------------------------------------------
// Tiled fp32 GEMM (final projection): C[M][N] = A[M][K] * B[N][K]^T + bias[n]
// ---------------------------------------------------------------------------
template <int BM, int BN, int BK>
__global__ __launch_bounds__(256)
void gemm_abt(const float* __restrict__ A, const float* __restrict__ B,
              const float* __restrict__ bias1,
              float* __restrict__ C, int M, int N, int K) {
    constexpr int NTX = BN / 4;
    constexpr int NTY = 256 / NTX;
    constexpr int TM  = BM / NTY;
    __shared__ float As[BM][BK + 1];
    __shared__ float Bs[BN][BK + 1];

    const int tid = threadIdx.x;
    const int tx = tid % NTX;
    const int ty = tid / NTX;
    const int m0 = blockIdx.y * BM;
    const int n0 = blockIdx.x * BN;

    float acc[TM][4];
    #pragma unroll
    for (int i = 0; i < TM; ++i)
        #pragma unroll
        for (int j = 0; j < 4; ++j) acc[i][j] = 0.f;

    for (int k0 = 0; k0 < K; k0 += BK) {
        constexpr int AV = BM * BK / 4;
        #pragma unroll
        for (int i = tid; i < AV; i += 256) {
            int r = i / (BK / 4), c4 = i % (BK / 4);
            float4 v = *(const float4*)(A + (size_t)(m0 + r) * K + k0 + c4 * 4);
            As[r][c4 * 4 + 0] = v.x; As[r][c4 * 4 + 1] = v.y;
            As[r][c4 * 4 + 2] = v.z; As[r][c4 * 4 + 3] = v.w;
        }
        constexpr int BV = BN * BK / 4;
        #pragma unroll
        for (int i = tid; i < BV; i += 256) {
            int r = i / (BK / 4), c4 = i % (BK / 4);
            float4 v = *(const float4*)(B + (size_t)(n0 + r) * K + k0 + c4 * 4);
            Bs[r][c4 * 4 + 0] = v.x; Bs[r][c4 * 4 + 1] = v.y;
            Bs[r][c4 * 4 + 2] = v.z; Bs[r][c4 * 4 + 3] = v.w;
        }
        __syncthreads();
        #pragma unroll
        for (int kk = 0; kk < BK; ++kk) {
            float a[TM], b[4];
            #pragma unroll
            for (int i = 0; i < TM; ++i) a[i] = As[ty * TM + i][kk];
            #pragma unroll
            for (int j = 0; j < 4; ++j) b[j] = Bs[tx * 4 + j][kk];
            #pragma unroll
            for (int i = 0; i < TM; ++i)
                #pragma unroll
                for (int j = 0; j < 4; ++j) acc[i][j] += a[i] * b[j];
        }
        __syncthreads();
    }

    #pragma unroll
    for (int j = 0; j < 4; ++j) {
        float bv = bias1 ? bias1[n0 + tx * 4 + j] : 0.f;
        #pragma unroll
        for (int i = 0; i < TM; ++i) acc[i][j] += bv;
    }
    #pragma unroll
    for (int i = 0; i < TM; ++i) {
        int m = m0 + ty * TM + i;
        float4 v = make_float4(acc[i][0], acc[i][1], acc[i][2], acc[i][3]);
        *(float4*)(C + (size_t)m * N + n0 + tx * 4) = v;
    }
}

// ---------------------------------------------------------------------------
__global__ void unpack_h(const u64* __restrict__ hp, float* __restrict__ out,
                         int n) {
    int i = blockIdx.x * blockDim.x + threadIdx.x;
    if (i < n) out[i] = __uint_as_float((unsigned)hp[i]);
}

// ---------------------------------------------------------------------------
// 32 WGs/layer x 1024 thr (16 waves). Lane = row (gate*16 + col_local).
// Layers 1/2: wave wv owns k-chunk [wv*64,+64) of concat [prev-h; own-h]:
//   wv<8 -> prev-h / Wih, wv>=8 -> own-h / Whh. Lane polls one element into
//   a VGPR; dot = 64x readlane-broadcast + fmac against w[64].
// Layer 0: wave wv owns own-h k [wv*32,+32) (lanes 0-31 poll); wave 15 also
//   handles x (32 floats of seq, weights in w[32..63]).
// ---------------------------------------------------------------------------
__global__ __launch_bounds__(NTH, 4)
void lstm_fused(const float* __restrict__ seq,
                const float* __restrict__ Wih1, const float* __restrict__ Whh1,
                const float* __restrict__ bih1, const float* __restrict__ bhh1,
                const float* __restrict__ Wih2, const float* __restrict__ Whh2,
                const float* __restrict__ bih2, const float* __restrict__ bhh2,
                const float* __restrict__ Wih3, const float* __restrict__ Whh3,
                const float* __restrict__ bih3, const float* __restrict__ bhh3,
                u64* __restrict__ hp) {
    __shared__ float part[2][NTH];      // [pb][wv*64 + row]

    const int blk   = blockIdx.x;
    const int layer = blk >> 5;
    const int g     = blk & 31;
    const int tid   = threadIdx.x;
    const int wv    = tid >> 6;          // 0..15
    const int lane  = tid & 63;          // = row (gate*16 + col_local)
    const int grow  = (lane >> 4) * HDIM + g * 16 + (lane & 15);

    const float* Wih = layer == 0 ? Wih1 : (layer == 1 ? Wih2 : Wih3);
    const float* Whh = layer == 0 ? Whh1 : (layer == 1 ? Whh2 : Whh3);
    const float* bih = layer == 0 ? bih1 : (layer == 1 ? bih2 : bih3);
    const float* bhh = layer == 0 ? bhh1 : (layer == 1 ? bhh2 : bhh3);

    // ---- 64 weight floats/lane (loop-constant indexing only) ----
    float w[64];
    #pragma unroll
    for (int m = 0; m < 64; ++m) w[m] = 0.f;
    if (layer == 0) {
        const float* wp = Whh + (size_t)grow * HDIM + wv * 32;
        #pragma unroll
        for (int i = 0; i < 8; ++i) {
            float4 v = ((const float4*)wp)[i];
            w[4*i+0]=v.x; w[4*i+1]=v.y; w[4*i+2]=v.z; w[4*i+3]=v.w;
        }
        if (wv == 15) {   // x weights -> w[32..63]
            const float* xp = Wih + (size_t)grow * 32;
            #pragma unroll
            for (int i = 0; i < 8; ++i) {
                float4 v = ((const float4*)xp)[i];
                w[32+4*i+0]=v.x; w[32+4*i+1]=v.y;
                w[32+4*i+2]=v.z; w[32+4*i+3]=v.w;
            }
        }
    } else {
        const float* wp = (wv < 8)
            ? Wih + (size_t)grow * HDIM + wv * 64
            : Whh + (size_t)grow * HDIM + (wv - 8) * 64;
        #pragma unroll
        for (int i = 0; i < 16; ++i) {
            float4 v = ((const float4*)wp)[i];
            w[4*i+0]=v.x; w[4*i+1]=v.y; w[4*i+2]=v.z; w[4*i+3]=v.w;
        }
    }
    #pragma unroll
    for (int m = 0; m < 64; ++m) asm volatile("" : "+v"(w[m]));

    const float brow = bih[grow] + bhh[grow];

    u64*       hpOwn  = hp + (size_t)layer * T_SEQ * HDIM;
    const u64* hpPrev = hp + (size_t)(layer > 0 ? layer - 1 : 0) * T_SEQ * HDIM;

    float c = 0.f;   // cell state (wave 0, lanes 0..15)

    for (unsigned t = 0; t < T_SEQ; ++t) {
        const int pb = t & 1;

        // ---- per-wave poll: chunk element straight into a VGPR ----
        float hval = 0.f;
        float xval = 0.f;
        if (layer == 0) {
            if (lane < 32 && t > 0) {
                const u64* ph = hpOwn + (size_t)(t - 1) * HDIM + wv * 32 + lane;
                u64 v;
                do { v = cohLoad(ph); } while ((unsigned)(v >> 32) != t);
                hval = __uint_as_float((unsigned)v);
            }
            if (wv == 15 && lane < 32)
                xval = seq[(size_t)t * 32 + lane];
        } else {
            if (wv < 8) {                        // prev-layer h[t], tag t+1
                const u64* px = hpPrev + (size_t)t * HDIM + wv * 64 + lane;
                u64 v;
                do { v = cohLoad(px); } while ((unsigned)(v >> 32) != t + 1u);
                hval = __uint_as_float((unsigned)v);
            } else if (t > 0) {                  // own h[t-1], tag t
                const u64* ph = hpOwn + (size_t)(t - 1) * HDIM
                              + (wv - 8) * 64 + lane;
                u64 v;
                do { v = cohLoad(ph); } while ((unsigned)(v >> 32) != t);
                hval = __uint_as_float((unsigned)v);
            }
        }

        // ---- dot: readlane broadcast + fmac, NO LDS ----
        float pe = 0.f, po = 0.f;
        if (layer == 0) {
            #pragma unroll
            for (int k = 0; k < 32; k += 2) {
                pe = fmaf(bcast(hval, k),     w[k],     pe);
                po = fmaf(bcast(hval, k + 1), w[k + 1], po);
            }
            if (wv == 15) {
                #pragma unroll
                for (int k = 0; k < 32; k += 2) {
                    pe = fmaf(bcast(xval, k),     w[32 + k],     pe);
                    po = fmaf(bcast(xval, k + 1), w[32 + k + 1], po);
                }
            }
        } else {
            #pragma unroll
            for (int k = 0; k < 64; k += 2) {
                pe = fmaf(bcast(hval, k),     w[k],     pe);
                po = fmaf(bcast(hval, k + 1), w[k + 1], po);
            }
        }
        part[pb][wv * 64 + lane] = pe + po;
        __syncthreads();

        // ---- wave 0: cross-wave sum, gates, ONE coalesced 128B publish ----
        if (wv == 0) {
            float tot = brow;
            #pragma unroll
            for (int wvv = 0; wvv < 16; ++wvv) tot += part[pb][wvv * 64 + lane];
            const int c16 = lane & 15;
            float ai = __shfl(tot, c16 +  0, 64);
            float af = __shfl(tot, c16 + 16, 64);
            float ag = __shfl(tot, c16 + 32, 64);
            float ao = __shfl(tot, c16 + 48, 64);
            if (lane < 16) {
                float iv = fsigmoid(ai);
                float fv = fsigmoid(af);
                float gv = ftanh(ag);
                float ov = fsigmoid(ao);
                c = fv * c + iv * gv;
                float h = ov * ftanh(c);
                u64 pkt = (u64)__float_as_uint(h) | ((u64)(t + 1u) << 32);
                cohStore(hpOwn + (size_t)t * HDIM + g * 16 + lane, pkt);
            }
        }
        // Other waves roll straight into polling t+1 (no pre-dot barrier:
        // each wave consumes only its own polled registers). part[] is
        // double-buffered; writes to part[pb] recur only at t+2, after
        // barrier(t+1), which wave 0 reaches only after its tail(t) reads.
    }
}

// ---------------------------------------------------------------------------
extern "C" void kernel_launch(void* const* d_in, const int* in_sizes, int n_in,
                              void* d_out, int out_size, void* d_ws, size_t ws_size,
                              hipStream_t stream) {
    const float* seq   = (const float*)d_in[0];
    const float* W_ih1 = (const float*)d_in[1];
    const float* W_hh1 = (const float*)d_in[2];
    const float* b_ih1 = (const float*)d_in[3];
    const float* b_hh1 = (const float*)d_in[4];
    const float* W_ih2 = (const float*)d_in[5];
    const float* W_hh2 = (const float*)d_in[6];
    const float* b_ih2 = (const float*)d_in[7];
    const float* b_hh2 = (const float*)d_in[8];
    const float* W_ih3 = (const float*)d_in[9];
    const float* W_hh3 = (const float*)d_in[10];
    const float* b_ih3 = (const float*)d_in[11];
    const float* b_hh3 = (const float*)d_in[12];
    const float* W_out = (const float*)d_in[13];
    const float* b_out = (const float*)d_in[14];
    float* out = (float*)d_out;

    // Workspace: hp[3][T][512] packed u64 (50.3MB); hs2 floats reuse the
    // dead layer-0 packed region after the recurrence.
    u64*   hp   = (u64*)d_ws;
    float* hs2f = (float*)d_ws;
    const u64* hp2 = hp + (size_t)2 * T_SEQ * HDIM;

    hipMemsetAsync(hp, 0, (size_t)3 * T_SEQ * HDIM * sizeof(u64), stream);

    lstm_fused<<<3 * NWG_L, NTH, 0, stream>>>(
        seq, W_ih1, W_hh1, b_ih1, b_hh1, W_ih2, W_hh2, b_ih2, b_hh2,
        W_ih3, W_hh3, b_ih3, b_hh3, hp);

    const int n = T_SEQ * HDIM;
    unpack_h<<<(n + 255) / 256, 256, 0, stream>>>(hp2, hs2f, n);

    gemm_abt<64, 32, 32><<<dim3(1, T_SEQ / 64), 256, 0, stream>>>(
        hs2f, W_out, b_out, out, T_SEQ, 32, HDIM);
}